// Round 5
// baseline (440.756 us; speedup 1.0000x reference)
//
#include <hip/hip_runtime.h>
#include <hip/hip_bf16.h>
#include <stdint.h>

#define S 4096
#define E 512
#define H 8
#define D 64
#define MROW 5000        // mask row stride (MAX_GENES)

typedef __hip_bfloat16 bf16;
typedef __attribute__((ext_vector_type(8))) short bf16x8;
typedef __attribute__((ext_vector_type(4))) float f32x4;

#define CMUL (0.125f * 1.4426950408889634f)  // scale * log2(e), folded into Q

// ---------------------------------------------------------------------------
// prep: all 2048 blocks convert fp32->bf16 (12 MB) via branch-structured
// segment select, then pack mask into TRANSPOSED bit matrix bitsT[word][row].
// Also zeroes the attn last-arriver counters (re-armed every iteration).
// ---------------------------------------------------------------------------
__global__ __launch_bounds__(256) void prep(
    const void* __restrict__ mask, unsigned long long* __restrict__ bitsT,
    const float* __restrict__ x,  const float* __restrict__ wq,
    const float* __restrict__ wk, const float* __restrict__ wv,
    const float* __restrict__ wo, const float* __restrict__ bq,
    const float* __restrict__ bk, const float* __restrict__ bv,
    const float* __restrict__ bo,
    bf16* __restrict__ xb, bf16* __restrict__ wcat, bf16* __restrict__ wob,
    bf16* __restrict__ bcat, bf16* __restrict__ bob,
    unsigned int* __restrict__ cnt)
{
    const int tid = threadIdx.x;
    const int b   = blockIdx.x;
    if (b == 0 && tid < 32) cnt[tid] = 0u;
    const int gid = b * 256 + tid;
    for (int g = gid; g < 786944; g += 524288) {
        const float* src; bf16* dst; int e;
        if (g < 524288) { src = x; dst = xb; e = g * 4; }
        else {
            int r = g - 524288;
            if      (r < 65536)  { src = wq; dst = wcat;          e = r * 4; }
            else if (r < 131072) { src = wk; dst = wcat + 262144; e = (r - 65536) * 4; }
            else if (r < 196608) { src = wv; dst = wcat + 524288; e = (r - 131072) * 4; }
            else if (r < 262144) { src = wo; dst = wob;           e = (r - 196608) * 4; }
            else if (r < 262272) { src = bq; dst = bcat;          e = (r - 262144) * 4; }
            else if (r < 262400) { src = bk; dst = bcat + 512;    e = (r - 262272) * 4; }
            else if (r < 262528) { src = bv; dst = bcat + 1024;   e = (r - 262400) * 4; }
            else                 { src = bo; dst = bob;           e = (r - 262528) * 4; }
        }
        float4 v = *(const float4*)(src + e);
        union { bf16 h[4]; uint2 u; } cv;
        cv.h[0] = (bf16)v.x; cv.h[1] = (bf16)v.y;
        cv.h[2] = (bf16)v.z; cv.h[3] = (bf16)v.w;
        *(uint2*)(dst + e) = cv.u;
    }
    {
        const unsigned int* mw32 = (const unsigned int*)mask;
        int lane = tid & 63;
        int hit = 0;
#pragma unroll
        for (int i = 0; i < 8; ++i) {
            unsigned int w = mw32[lane + i * 64];
            if (w > 1u && (w & 0xFEFEFEFEu) == 0u) hit = 1;
        }
        const bool isbyte = (__ballot(hit) != 0ull);
        int wid  = (b * 256 + tid) >> 6;
        int nwav = (2048 * 256) >> 6;
        int total = (S / 64) * S;
        for (int w = wid; w < total; w += nwav) {
            int word = w >> 12;          // 0..63
            int row  = w & (S - 1);      // 0..4095
            int col  = word * 64 + lane;
            unsigned int v;
            if (isbyte) v = ((const unsigned char*)mask)[(size_t)row * MROW + col];
            else        v = ((const unsigned int*)mask)[(size_t)row * MROW + col];
            unsigned long long bb = __ballot(v != 0u);
            if (lane == 0) bitsT[(size_t)word * S + row] = bb;
        }
    }
}

// ---------------------------------------------------------------------------
// QKV GEMM, 128x64 tile (BM=128 BN=64 BK=64). 4 waves, each owns a 32x64
// sub-tile (acc[2][4]). out planar Q|K|V, Q pre-scaled by CMUL.
// ---------------------------------------------------------------------------
__global__ __launch_bounds__(256) void gemm_qkv(const bf16* __restrict__ A,
                                                const bf16* __restrict__ W,
                                                const bf16* __restrict__ bias,
                                                bf16* __restrict__ out)
{
    __shared__ bf16 As[128][72];
    __shared__ bf16 Bs[64][72];
    const int tid  = threadIdx.x;
    const int wid  = tid >> 6, lane = tid & 63;
    const int quad = lane >> 4, l15 = lane & 15;
    const int nbase = blockIdx.x * 64;
    const int mbase = blockIdx.y * 128;
    const int wr = wid * 32;

    f32x4 acc[2][4];
#pragma unroll
    for (int i = 0; i < 2; ++i)
#pragma unroll
        for (int j = 0; j < 4; ++j) acc[i][j] = (f32x4){0.f, 0.f, 0.f, 0.f};

    for (int kt = 0; kt < E / 64; ++kt) {
        const int kb = kt * 64;
        __syncthreads();
#pragma unroll
        for (int i = 0; i < 4; ++i) {
            int slot = tid + i * 256;
            int row = slot >> 3, kg = slot & 7;
            *(uint4*)&As[row][kg * 8] = *(const uint4*)&A[(size_t)(mbase + row) * E + kb + kg * 8];
        }
#pragma unroll
        for (int i = 0; i < 2; ++i) {
            int slot = tid + i * 256;
            int row = slot >> 3, kg = slot & 7;
            *(uint4*)&Bs[row][kg * 8] = *(const uint4*)&W[(size_t)(nbase + row) * E + kb + kg * 8];
        }
        __syncthreads();
        bf16x8 a0[2], a1[2];
#pragma unroll
        for (int mt = 0; mt < 2; ++mt) {
            a0[mt] = *(bf16x8*)&As[wr + mt * 16 + l15][quad * 8];
            a1[mt] = *(bf16x8*)&As[wr + mt * 16 + l15][32 + quad * 8];
        }
#pragma unroll
        for (int nt = 0; nt < 4; ++nt) {
            bf16x8 b0 = *(bf16x8*)&Bs[nt * 16 + l15][quad * 8];
            bf16x8 b1 = *(bf16x8*)&Bs[nt * 16 + l15][32 + quad * 8];
#pragma unroll
            for (int mt = 0; mt < 2; ++mt) {
                acc[mt][nt] = __builtin_amdgcn_mfma_f32_16x16x32_bf16(a0[mt], b0, acc[mt][nt], 0, 0, 0);
                acc[mt][nt] = __builtin_amdgcn_mfma_f32_16x16x32_bf16(a1[mt], b1, acc[mt][nt], 0, 0, 0);
            }
        }
    }
#pragma unroll
    for (int nt = 0; nt < 4; ++nt) {
        int col = nbase + nt * 16 + l15;
        float bv = (float)bias[col];
        int t = col >> 9, hh = (col >> 6) & 7, d = col & 63;
#pragma unroll
        for (int mt = 0; mt < 2; ++mt)
#pragma unroll
            for (int r = 0; r < 4; ++r) {
                int row = mbase + wr + mt * 16 + quad * 4 + r;
                float v = acc[mt][nt][r] + bv;
                if (t == 0) v *= CMUL;
                out[((size_t)t * H + hh) * S * D + (size_t)row * D + d] = (bf16)v;
            }
    }
}

// ---------------------------------------------------------------------------
// Fused flash attention + LAST-ARRIVER K-SPLIT COMBINE.
// Main loop identical to round 4 (32 q/warp, swapped QK, sign-bit mask AND,
// +0x8000/v_perm pack, swizzled K/V/Ps LDS). After the epilogue, each block
// fences + atomicAdd's cnt[qb]; the 32nd (last) block of the (h x split)
// group reduces all splits for its 128 rows (L2/L3-resident, ~1MB) and
// writes the normalized bf16 Ab panel — the separate combine kernel (and
// its launch boundary) is gone. No spinning: deadlock-impossible.
// grid (S/128, H, nsplit), block 256.
// ---------------------------------------------------------------------------
__global__ __launch_bounds__(256) void attn(const bf16* __restrict__ Qp,
                                            const bf16* __restrict__ Kp,
                                            const bf16* __restrict__ Vp,
                                            const unsigned long long* __restrict__ bitsT,
                                            float* __restrict__ Opart,
                                            float* __restrict__ Lpart,
                                            bf16* __restrict__ Ab,
                                            unsigned int* __restrict__ cnt,
                                            int ktper)
{
    __shared__ __align__(16) char smem[32768];
    bf16 (*Ps)[32][64] = (bf16(*)[32][64])smem;             // 4 x 32q x 64t swizzled
    bf16 (*Ks)[64]     = (bf16(*)[64])(smem + 16384);       // 64x64 swizzled
    bf16 (*Vts)[64]    = (bf16(*)[64])(smem + 24576);       // 64x64 swizzled V^T

    const int tid  = threadIdx.x;
    const int wid  = tid >> 6, lane = tid & 63;
    const int quad = lane >> 4, l15 = lane & 15;
    const int qb = blockIdx.x, h = blockIdx.y, split = blockIdx.z;
    const int qbase = qb * 128;
    const int m0 = wid * 32;
    const bf16* Qh = Qp + (size_t)h * S * D;
    const bf16* Kh = Kp + (size_t)h * S * D;
    const bf16* Vh = Vp + (size_t)h * S * D;

    const int krow0 = tid >> 3, kkg = tid & 7;
    const int krow1 = (tid + 256) >> 3;
    const int ksw0 = (kkg ^ (krow0 & 7)) * 8;
    const int ksw1 = (kkg ^ (krow1 & 7)) * 8;
    const int vt0 = (tid & 31) * 2, vd0 = (tid >> 5) * 8;

    // Q fragments direct from global: lane = query row (B-operand layout);
    // two query sub-tiles per warp (u=0: rows m0+l15, u=1: rows m0+16+l15)
    const bf16* qr0 = Qh + (size_t)(qbase + m0 + l15) * D;
    bf16x8 aq00 = *(const bf16x8*)(qr0 + quad * 8);
    bf16x8 aq01 = *(const bf16x8*)(qr0 + 32 + quad * 8);
    bf16x8 aq10 = *(const bf16x8*)(qr0 + 16 * D + quad * 8);
    bf16x8 aq11 = *(const bf16x8*)(qr0 + 16 * D + 32 + quad * 8);

    // ones B-fragment for l-sum MFMA (col 0 only)
    bf16x8 bl;
    {
        union { short s; bf16 b; } one; one.b = (bf16)1.0f;
        short v = (l15 == 0) ? one.s : (short)0;
#pragma unroll
        for (int j = 0; j < 8; ++j) bl[j] = v;
    }

    f32x4 o[4][2];
#pragma unroll
    for (int dt = 0; dt < 4; ++dt)
#pragma unroll
        for (int u = 0; u < 2; ++u) o[dt][u] = (f32x4){0.f, 0.f, 0.f, 0.f};
    f32x4 accl[2];
    accl[0] = (f32x4){0.f, 0.f, 0.f, 0.f};
    accl[1] = (f32x4){0.f, 0.f, 0.f, 0.f};

    const int kt0 = split * ktper, kt1 = kt0 + ktper;

    // strength-reduced prefetch pointers: advance by one K-tile (64*D) per kt
    const bf16* kp0 = Kh + (size_t)(kt0 * 64 + krow0) * D + kkg * 8;
    const bf16* kp1 = Kh + (size_t)(kt0 * 64 + krow1) * D + kkg * 8;
    const bf16* vp0 = Vh + (size_t)(kt0 * 64 + vt0) * D + vd0;
    const bf16* vp1 = Vh + (size_t)(kt0 * 64 + vt0 + 1) * D + vd0;
    uint4 kq0 = *(const uint4*)kp0;
    uint4 kq1 = *(const uint4*)kp1;
    uint4 vq0 = *(const uint4*)vp0;
    uint4 vq1 = *(const uint4*)vp1;

    // transposed mask: one 8B word per lane per query sub-tile, coalesced
    const unsigned long long* mb0 = bitsT + (size_t)kt0 * S + qbase + m0 + l15;
    const unsigned long long* mb1 = mb0 + 16;

    const int ksw_rd = (l15 & 7);               // K/V/P read-write swizzle key
#pragma unroll 1
    for (int kt = kt0; kt < kt1; ++kt) {
        __syncthreads();   // previous tile consumed
        *(uint4*)&Ks[krow0][ksw0] = kq0;
        *(uint4*)&Ks[krow1][ksw1] = kq1;
        {
            const unsigned int* w0 = (const unsigned int*)&vq0;
            const unsigned int* w1 = (const unsigned int*)&vq1;
#pragma unroll
            for (int j = 0; j < 8; ++j) {
                unsigned int pk = __builtin_amdgcn_perm(
                    w1[j >> 1], w0[j >> 1],
                    (j & 1) ? 0x07060302u : 0x05040100u);
                *(unsigned int*)&Vts[vd0 + j][vt0 ^ (j * 8)] = pk;
            }
        }
        if (kt + 1 < kt1) {
            kp0 += 64 * D; kp1 += 64 * D; vp0 += 64 * D; vp1 += 64 * D;
            kq0 = *(const uint4*)kp0;
            kq1 = *(const uint4*)kp1;
            vq0 = *(const uint4*)vp0;
            vq1 = *(const uint4*)vp1;
        }
        unsigned long long mw0 = *mb0; mb0 += S;
        unsigned long long mw1 = *mb1; mb1 += S;
        __syncthreads();   // K/V tile visible

        // S^T = K Q^T (exp2 domain): A = K frag (lane=token), B = Q frag.
        // One K-frag read pair feeds BOTH query sub-tiles.
        f32x4 sc[2][4];
        {
            f32x4 z = (f32x4){0.f, 0.f, 0.f, 0.f};
            __builtin_amdgcn_s_setprio(1);
#pragma unroll
            for (int nt = 0; nt < 4; ++nt) {
                bf16x8 kb0 = *(bf16x8*)&Ks[nt * 16 + l15][(quad ^ ksw_rd) * 8];
                bf16x8 kb1 = *(bf16x8*)&Ks[nt * 16 + l15][((quad + 4) ^ ksw_rd) * 8];
                sc[0][nt] = __builtin_amdgcn_mfma_f32_16x16x32_bf16(kb0, aq00, z, 0, 0, 0);
                sc[0][nt] = __builtin_amdgcn_mfma_f32_16x16x32_bf16(kb1, aq01, sc[0][nt], 0, 0, 0);
                sc[1][nt] = __builtin_amdgcn_mfma_f32_16x16x32_bf16(kb0, aq10, z, 0, 0, 0);
                sc[1][nt] = __builtin_amdgcn_mfma_f32_16x16x32_bf16(kb1, aq11, sc[1][nt], 0, 0, 0);
            }
            __builtin_amdgcn_s_setprio(0);
        }
        // lane holds P^T: query=l15 (per sub-tile u), tokens nt*16+quad*4+{0..3}.
        // Mask post-exp2 via sign-extended bit AND; +0x8000 round-half-up bias
        // then v_perm pair-pack. Ps write col XOR-swizzled by (l15&7)*8.
#pragma unroll
        for (int u = 0; u < 2; ++u) {
            const unsigned long long sh = (u ? mw1 : mw0) >> (quad * 4);
            const unsigned int wlo = (unsigned int)sh;
            const unsigned int whi = (unsigned int)(sh >> 32);
#pragma unroll
            for (int nt = 0; nt < 4; ++nt) {
                const unsigned int wsel = (nt < 2) ? wlo : whi;
                unsigned int a[4];
#pragma unroll
                for (int r = 0; r < 4; ++r) {
                    const int bit = (nt & 1) * 16 + r;     // compile-time
                    unsigned int m = (unsigned int)((int)(wsel << (31 - bit)) >> 31);
                    a[r] = (__float_as_uint(__builtin_amdgcn_exp2f(sc[u][nt][r])) & m) + 0x8000u;
                }
                uint2 pk;
                pk.x = __builtin_amdgcn_perm(a[1], a[0], 0x07060302u);
                pk.y = __builtin_amdgcn_perm(a[3], a[2], 0x07060302u);
                *(uint2*)&Ps[wid][u * 16 + l15][(nt * 16 + quad * 4) ^ (ksw_rd * 8)] = pk;
            }
        }
        // O += P V ; l += P 1   (P A-frag: row = query, contiguous tokens;
        // read col carries the same XOR key (l15&7)*8)
        bf16x8 ap00 = *(bf16x8*)&Ps[wid][l15][(quad * 8) ^ (ksw_rd * 8)];
        bf16x8 ap01 = *(bf16x8*)&Ps[wid][l15][(32 + quad * 8) ^ (ksw_rd * 8)];
        bf16x8 ap10 = *(bf16x8*)&Ps[wid][16 + l15][(quad * 8) ^ (ksw_rd * 8)];
        bf16x8 ap11 = *(bf16x8*)&Ps[wid][16 + l15][(32 + quad * 8) ^ (ksw_rd * 8)];
        __builtin_amdgcn_s_setprio(1);
        accl[0] = __builtin_amdgcn_mfma_f32_16x16x32_bf16(ap00, bl, accl[0], 0, 0, 0);
        accl[0] = __builtin_amdgcn_mfma_f32_16x16x32_bf16(ap01, bl, accl[0], 0, 0, 0);
        accl[1] = __builtin_amdgcn_mfma_f32_16x16x32_bf16(ap10, bl, accl[1], 0, 0, 0);
        accl[1] = __builtin_amdgcn_mfma_f32_16x16x32_bf16(ap11, bl, accl[1], 0, 0, 0);
#pragma unroll
        for (int dt = 0; dt < 4; ++dt) {
            bf16x8 bv0 = *(bf16x8*)&Vts[dt * 16 + l15][(quad ^ ksw_rd) * 8];
            bf16x8 bv1 = *(bf16x8*)&Vts[dt * 16 + l15][((quad + 4) ^ ksw_rd) * 8];
            o[dt][0] = __builtin_amdgcn_mfma_f32_16x16x32_bf16(ap00, bv0, o[dt][0], 0, 0, 0);
            o[dt][0] = __builtin_amdgcn_mfma_f32_16x16x32_bf16(ap01, bv1, o[dt][0], 0, 0, 0);
            o[dt][1] = __builtin_amdgcn_mfma_f32_16x16x32_bf16(ap10, bv0, o[dt][1], 0, 0, 0);
            o[dt][1] = __builtin_amdgcn_mfma_f32_16x16x32_bf16(ap11, bv1, o[dt][1], 0, 0, 0);
        }
        __builtin_amdgcn_s_setprio(0);
    }
    // epilogue: fp32 partials; O/l C-layout rows = u*16 + quad*4 + r
    float* Op = Opart + (size_t)(split * H + h) * S * D;
    float* Lp = Lpart + (size_t)(split * H + h) * S;
#pragma unroll
    for (int u = 0; u < 2; ++u)
#pragma unroll
        for (int r = 0; r < 4; ++r) {
            int row = qbase + m0 + u * 16 + quad * 4 + r;
            if (l15 == 0) Lp[row] = accl[u][r];
#pragma unroll
            for (int dt = 0; dt < 4; ++dt)
                Op[(size_t)row * D + dt * 16 + l15] = o[dt][u][r];
        }

    // ---- fused K-split combine: last arriver of this qb group reduces ----
    const int nsplit = (S / 64) / ktper;
    __threadfence();               // publish this block's Opart/Lpart (release)
    __syncthreads();               // all threads fenced before tid0 publishes
    if (tid == 0) *(volatile int*)smem = (int)atomicAdd(&cnt[qb], 1u);
    __syncthreads();
    if (*(volatile int*)smem == H * nsplit - 1) {
        __threadfence();           // acquire: see all groups' writes
        const size_t oh = (size_t)H * S * D;
#pragma unroll 1
        for (int it = 0; it < 32; ++it) {
            int g = it * 256 + tid;                 // 8192 tasks = 128 rows x 64 col-groups
            int row = qbase + (g >> 6);
            int cg  = g & 63;
            int hh  = cg >> 3;
            int d0  = (cg & 7) * 8;
            size_t base = ((size_t)hh * S + row) * D + d0;
            float a[8] = {0.f, 0.f, 0.f, 0.f, 0.f, 0.f, 0.f, 0.f};
            float l = 0.f;
#pragma unroll
            for (int s = 0; s < 4; ++s) {
                if (s >= nsplit) break;
                float4 p0 = *(const float4*)(Opart + (size_t)s * oh + base);
                float4 p1 = *(const float4*)(Opart + (size_t)s * oh + base + 4);
                a[0] += p0.x; a[1] += p0.y; a[2] += p0.z; a[3] += p0.w;
                a[4] += p1.x; a[5] += p1.y; a[6] += p1.z; a[7] += p1.w;
                l += Lpart[(size_t)s * H * S + (size_t)hh * S + row];
            }
            float inv = (l > 0.f) ? 1.f / l : 0.f;
            union { bf16 hb[8]; uint4 u; } cv;
#pragma unroll
            for (int j = 0; j < 8; ++j) cv.hb[j] = (bf16)(a[j] * inv);
            *(uint4*)&Ab[(size_t)row * E + cg * 8] = cv.u;
        }
        if (tid == 0) cnt[qb] = 0u;   // re-arm (prep also zeroes each iter)
    }
}

// ---------------------------------------------------------------------------
// Output GEMM, 128x64 tile: out = Ab @ Wo^T + bo, fp32.
// grid (8, 32) = 256 blocks = exactly 1/CU.
// ---------------------------------------------------------------------------
__global__ __launch_bounds__(256) void gemm_out(const bf16* __restrict__ A,
                                                const bf16* __restrict__ W,
                                                const bf16* __restrict__ bias,
                                                float* __restrict__ out)
{
    __shared__ bf16 As[128][72];
    __shared__ bf16 Bs[64][72];
    const int tid  = threadIdx.x;
    const int wid  = tid >> 6, lane = tid & 63;
    const int quad = lane >> 4, l15 = lane & 15;
    const int nbase = blockIdx.x * 64;
    const int mbase = blockIdx.y * 128;
    const int wr = wid * 32;

    f32x4 acc[2][4];
#pragma unroll
    for (int i = 0; i < 2; ++i)
#pragma unroll
        for (int j = 0; j < 4; ++j) acc[i][j] = (f32x4){0.f, 0.f, 0.f, 0.f};

    for (int kt = 0; kt < E / 64; ++kt) {
        const int kb = kt * 64;
        __syncthreads();
#pragma unroll
        for (int i = 0; i < 4; ++i) {
            int slot = tid + i * 256;
            int row = slot >> 3, kg = slot & 7;
            *(uint4*)&As[row][kg * 8] = *(const uint4*)&A[(size_t)(mbase + row) * E + kb + kg * 8];
        }
#pragma unroll
        for (int i = 0; i < 2; ++i) {
            int slot = tid + i * 256;
            int row = slot >> 3, kg = slot & 7;
            *(uint4*)&Bs[row][kg * 8] = *(const uint4*)&W[(size_t)(nbase + row) * E + kb + kg * 8];
        }
        __syncthreads();
        bf16x8 a0[2], a1[2];
#pragma unroll
        for (int mt = 0; mt < 2; ++mt) {
            a0[mt] = *(bf16x8*)&As[wr + mt * 16 + l15][quad * 8];
            a1[mt] = *(bf16x8*)&As[wr + mt * 16 + l15][32 + quad * 8];
        }
#pragma unroll
        for (int nt = 0; nt < 4; ++nt) {
            bf16x8 b0 = *(bf16x8*)&Bs[nt * 16 + l15][quad * 8];
            bf16x8 b1 = *(bf16x8*)&Bs[nt * 16 + l15][32 + quad * 8];
#pragma unroll
            for (int mt = 0; mt < 2; ++mt) {
                acc[mt][nt] = __builtin_amdgcn_mfma_f32_16x16x32_bf16(a0[mt], b0, acc[mt][nt], 0, 0, 0);
                acc[mt][nt] = __builtin_amdgcn_mfma_f32_16x16x32_bf16(a1[mt], b1, acc[mt][nt], 0, 0, 0);
            }
        }
    }
#pragma unroll
    for (int nt = 0; nt < 4; ++nt) {
        int col = nbase + nt * 16 + l15;
        float bv = (float)bias[col];
#pragma unroll
        for (int mt = 0; mt < 2; ++mt)
#pragma unroll
            for (int r = 0; r < 4; ++r) {
                int row = mbase + wr + mt * 16 + quad * 4 + r;
                out[(size_t)row * E + col] = acc[mt][nt][r] + bv;
            }
    }
}

// ---------------------------------------------------------------------------
extern "C" void kernel_launch(void* const* d_in, const int* in_sizes, int n_in,
                              void* d_out, int out_size, void* d_ws, size_t ws_size,
                              hipStream_t stream)
{
    char* ws = (char*)d_ws;
    const size_t MB = (size_t)1 << 20;
    bf16* Qw   = (bf16*)(ws + 0 * MB);        // 12 MB: Q|K|V planar cat
    bf16* Kw   = (bf16*)(ws + 4 * MB);
    bf16* Vw   = (bf16*)(ws + 8 * MB);
    bf16* Ab   = (bf16*)(ws + 12 * MB);       // 4 MB combined attn out (bf16)
    unsigned long long* bitsT = (unsigned long long*)(ws + 16 * MB); // 2 MB
    bf16* xb   = (bf16*)(ws + 18 * MB);       // 4 MB
    bf16* Wcat = (bf16*)(ws + 22 * MB);       // 1.5 MB
    bf16* Wob  = (bf16*)(ws + 24 * MB);       // 0.5 MB
    bf16* bcat = (bf16*)(ws + 25 * MB);
    bf16* bob  = (bf16*)(ws + 25 * MB + 8192);
    unsigned int* cnt = (unsigned int*)(ws + 25 * MB + 32768);  // 32 counters
    float* Opart = (float*)(ws + 26 * MB);    // nsplit x 8 MB

    int nsplit = (ws_size >= 59 * MB) ? 4 : 2;
    int ktper  = (S / 64) / nsplit;
    float* Lpart = (float*)(ws + 26 * MB + (size_t)nsplit * 8 * MB);

    hipLaunchKernelGGL(prep, dim3(2048), dim3(256), 0, stream,
                       d_in[9], bitsT,
                       (const float*)d_in[0], (const float*)d_in[1],
                       (const float*)d_in[3], (const float*)d_in[5],
                       (const float*)d_in[7], (const float*)d_in[2],
                       (const float*)d_in[4], (const float*)d_in[6],
                       (const float*)d_in[8],
                       xb, Wcat, Wob, bcat, bob, cnt);
    hipLaunchKernelGGL(gemm_qkv, dim3(24, 32), dim3(256), 0, stream,
                       xb, Wcat, bcat, Qw);
    hipLaunchKernelGGL(attn, dim3(S / 128, H, nsplit), dim3(256), 0, stream,
                       Qw, Kw, Vw, bitsT, Opart, Lpart, Ab, cnt, ktper);
    hipLaunchKernelGGL(gemm_out, dim3(8, 32), dim3(256), 0, stream,
                       Ab, Wob, bob, (float*)d_out);
}

// Round 6
// 264.128 us; speedup vs baseline: 1.6687x; 1.6687x over previous
//
#include <hip/hip_runtime.h>
#include <hip/hip_bf16.h>
#include <stdint.h>

#define S 4096
#define E 512
#define H 8
#define D 64
#define MROW 5000        // mask row stride (MAX_GENES)

typedef __hip_bfloat16 bf16;
typedef __attribute__((ext_vector_type(8))) short bf16x8;
typedef __attribute__((ext_vector_type(4))) float f32x4;

#define CMUL (0.125f * 1.4426950408889634f)  // scale * log2(e), folded into Q

// ---------------------------------------------------------------------------
// prep: all 2048 blocks convert fp32->bf16 (12 MB) via branch-structured
// segment select, then pack mask into TRANSPOSED bit matrix bitsT[word][row].
// ---------------------------------------------------------------------------
__global__ __launch_bounds__(256) void prep(
    const void* __restrict__ mask, unsigned long long* __restrict__ bitsT,
    const float* __restrict__ x,  const float* __restrict__ wq,
    const float* __restrict__ wk, const float* __restrict__ wv,
    const float* __restrict__ wo, const float* __restrict__ bq,
    const float* __restrict__ bk, const float* __restrict__ bv,
    const float* __restrict__ bo,
    bf16* __restrict__ xb, bf16* __restrict__ wcat, bf16* __restrict__ wob,
    bf16* __restrict__ bcat, bf16* __restrict__ bob)
{
    const int tid = threadIdx.x;
    const int b   = blockIdx.x;
    const int gid = b * 256 + tid;
    for (int g = gid; g < 786944; g += 524288) {
        const float* src; bf16* dst; int e;
        if (g < 524288) { src = x; dst = xb; e = g * 4; }
        else {
            int r = g - 524288;
            if      (r < 65536)  { src = wq; dst = wcat;          e = r * 4; }
            else if (r < 131072) { src = wk; dst = wcat + 262144; e = (r - 65536) * 4; }
            else if (r < 196608) { src = wv; dst = wcat + 524288; e = (r - 131072) * 4; }
            else if (r < 262144) { src = wo; dst = wob;           e = (r - 196608) * 4; }
            else if (r < 262272) { src = bq; dst = bcat;          e = (r - 262144) * 4; }
            else if (r < 262400) { src = bk; dst = bcat + 512;    e = (r - 262272) * 4; }
            else if (r < 262528) { src = bv; dst = bcat + 1024;   e = (r - 262400) * 4; }
            else                 { src = bo; dst = bob;           e = (r - 262528) * 4; }
        }
        float4 v = *(const float4*)(src + e);
        union { bf16 h[4]; uint2 u; } cv;
        cv.h[0] = (bf16)v.x; cv.h[1] = (bf16)v.y;
        cv.h[2] = (bf16)v.z; cv.h[3] = (bf16)v.w;
        *(uint2*)(dst + e) = cv.u;
    }
    {
        const unsigned int* mw32 = (const unsigned int*)mask;
        int lane = tid & 63;
        int hit = 0;
#pragma unroll
        for (int i = 0; i < 8; ++i) {
            unsigned int w = mw32[lane + i * 64];
            if (w > 1u && (w & 0xFEFEFEFEu) == 0u) hit = 1;
        }
        const bool isbyte = (__ballot(hit) != 0ull);
        int wid  = (b * 256 + tid) >> 6;
        int nwav = (2048 * 256) >> 6;
        int total = (S / 64) * S;
        for (int w = wid; w < total; w += nwav) {
            int word = w >> 12;          // 0..63
            int row  = w & (S - 1);      // 0..4095
            int col  = word * 64 + lane;
            unsigned int v;
            if (isbyte) v = ((const unsigned char*)mask)[(size_t)row * MROW + col];
            else        v = ((const unsigned int*)mask)[(size_t)row * MROW + col];
            unsigned long long bb = __ballot(v != 0u);
            if (lane == 0) bitsT[(size_t)word * S + row] = bb;
        }
    }
}

// ---------------------------------------------------------------------------
// QKV GEMM: C(64x64 tile) = A(Mx512) @ W^T + bias, N=1536 fused (r3-best).
// out planar Q|K|V, each [h][s][64] bf16; Q pre-scaled by CMUL.
// ---------------------------------------------------------------------------
__global__ __launch_bounds__(256) void gemm_qkv(const bf16* __restrict__ A,
                                                const bf16* __restrict__ W,
                                                const bf16* __restrict__ bias,
                                                bf16* __restrict__ out)
{
    __shared__ bf16 As[64][72];
    __shared__ bf16 Bs[64][72];
    const int tid  = threadIdx.x;
    const int wid  = tid >> 6, lane = tid & 63;
    const int quad = lane >> 4, l15 = lane & 15;
    const int nbase = blockIdx.x * 64;
    const int mbase = blockIdx.y * 64;
    const int m0 = wid * 16;

    f32x4 acc[4];
#pragma unroll
    for (int i = 0; i < 4; ++i) acc[i] = (f32x4){0.f, 0.f, 0.f, 0.f};

    for (int kt = 0; kt < E / 64; ++kt) {
        const int kb = kt * 64;
        __syncthreads();
#pragma unroll
        for (int i = 0; i < 2; ++i) {
            int slot = tid + i * 256;
            int row = slot >> 3, kg = slot & 7;
            *(uint4*)&As[row][kg * 8] = *(const uint4*)&A[(size_t)(mbase + row) * E + kb + kg * 8];
            *(uint4*)&Bs[row][kg * 8] = *(const uint4*)&W[(size_t)(nbase + row) * E + kb + kg * 8];
        }
        __syncthreads();
        bf16x8 a0 = *(bf16x8*)&As[m0 + l15][quad * 8];
        bf16x8 a1 = *(bf16x8*)&As[m0 + l15][32 + quad * 8];
#pragma unroll
        for (int nt = 0; nt < 4; ++nt) {
            bf16x8 b0 = *(bf16x8*)&Bs[nt * 16 + l15][quad * 8];
            bf16x8 b1 = *(bf16x8*)&Bs[nt * 16 + l15][32 + quad * 8];
            acc[nt] = __builtin_amdgcn_mfma_f32_16x16x32_bf16(a0, b0, acc[nt], 0, 0, 0);
            acc[nt] = __builtin_amdgcn_mfma_f32_16x16x32_bf16(a1, b1, acc[nt], 0, 0, 0);
        }
    }
#pragma unroll
    for (int nt = 0; nt < 4; ++nt) {
        int col = nbase + nt * 16 + l15;
        float bv = (float)bias[col];
#pragma unroll
        for (int r = 0; r < 4; ++r) {
            int row = mbase + m0 + quad * 4 + r;
            float v = acc[nt][r] + bv;
            int t = col >> 9, hh = (col >> 6) & 7, d = col & 63;
            if (t == 0) v *= CMUL;
            out[((size_t)t * H + hh) * S * D + (size_t)row * D + d] = (bf16)v;
        }
    }
}

// ---------------------------------------------------------------------------
// Fused flash attention, 32 queries/warp (128/block). Operand-swapped QK
// (P^T layout). The bf16 round-half-up bias (+0x8000 on f32 bits) is FOLDED
// into the QK MFMA C-init (log2(1+2^-9)): exp2 arrives pre-biased, so the
// pack is just bits(exp2) & signbit-mask + v_perm (saves 32 v_add/wave-kt;
// the systematic x(1+2^-9) cancels in l-normalization). LDS=32768 exactly
// (swizzled unpadded Ps) -> 5 blocks/CU when grid allows; supports ragged
// K-splits (kt1 = min(64, kt0+ktper)) for nsplit=5 = 1280 blocks = 5/CU.
// grid (S/128, H, nsplit), block 256.
// ---------------------------------------------------------------------------
__global__ __launch_bounds__(256) void attn(const bf16* __restrict__ Qp,
                                            const bf16* __restrict__ Kp,
                                            const bf16* __restrict__ Vp,
                                            const unsigned long long* __restrict__ bitsT,
                                            float* __restrict__ Opart,
                                            float* __restrict__ Lpart,
                                            int ktper)
{
    __shared__ __align__(16) char smem[32768];
    bf16 (*Ps)[32][64] = (bf16(*)[32][64])smem;             // 4 x 32q x 64t swizzled
    bf16 (*Ks)[64]     = (bf16(*)[64])(smem + 16384);       // 64x64 swizzled
    bf16 (*Vts)[64]    = (bf16(*)[64])(smem + 24576);       // 64x64 swizzled V^T

    const int tid  = threadIdx.x;
    const int wid  = tid >> 6, lane = tid & 63;
    const int quad = lane >> 4, l15 = lane & 15;
    const int qb = blockIdx.x, h = blockIdx.y, split = blockIdx.z;
    const int qbase = qb * 128;
    const int m0 = wid * 32;
    const bf16* Qh = Qp + (size_t)h * S * D;
    const bf16* Kh = Kp + (size_t)h * S * D;
    const bf16* Vh = Vp + (size_t)h * S * D;

    const int krow0 = tid >> 3, kkg = tid & 7;
    const int krow1 = (tid + 256) >> 3;
    const int ksw0 = (kkg ^ (krow0 & 7)) * 8;
    const int ksw1 = (kkg ^ (krow1 & 7)) * 8;
    const int vt0 = (tid & 31) * 2, vd0 = (tid >> 5) * 8;

    // Q fragments direct from global: lane = query row (B-operand layout);
    // two query sub-tiles per warp (u=0: rows m0+l15, u=1: rows m0+16+l15)
    const bf16* qr0 = Qh + (size_t)(qbase + m0 + l15) * D;
    bf16x8 aq00 = *(const bf16x8*)(qr0 + quad * 8);
    bf16x8 aq01 = *(const bf16x8*)(qr0 + 32 + quad * 8);
    bf16x8 aq10 = *(const bf16x8*)(qr0 + 16 * D + quad * 8);
    bf16x8 aq11 = *(const bf16x8*)(qr0 + 16 * D + 32 + quad * 8);

    // ones B-fragment for l-sum MFMA (col 0 only)
    bf16x8 bl;
    {
        union { short s; bf16 b; } one; one.b = (bf16)1.0f;
        short v = (l15 == 0) ? one.s : (short)0;
#pragma unroll
        for (int j = 0; j < 8; ++j) bl[j] = v;
    }

    f32x4 o[4][2];
#pragma unroll
    for (int dt = 0; dt < 4; ++dt)
#pragma unroll
        for (int u = 0; u < 2; ++u) o[dt][u] = (f32x4){0.f, 0.f, 0.f, 0.f};
    f32x4 accl[2];
    accl[0] = (f32x4){0.f, 0.f, 0.f, 0.f};
    accl[1] = (f32x4){0.f, 0.f, 0.f, 0.f};

    const int kt0 = split * ktper;
    const int kt1 = min(S / 64, kt0 + ktper);   // ragged tail for nsplit=5

    // strength-reduced prefetch pointers: advance by one K-tile (64*D) per kt
    const bf16* kp0 = Kh + (size_t)(kt0 * 64 + krow0) * D + kkg * 8;
    const bf16* kp1 = Kh + (size_t)(kt0 * 64 + krow1) * D + kkg * 8;
    const bf16* vp0 = Vh + (size_t)(kt0 * 64 + vt0) * D + vd0;
    const bf16* vp1 = Vh + (size_t)(kt0 * 64 + vt0 + 1) * D + vd0;
    uint4 kq0 = *(const uint4*)kp0;
    uint4 kq1 = *(const uint4*)kp1;
    uint4 vq0 = *(const uint4*)vp0;
    uint4 vq1 = *(const uint4*)vp1;

    // transposed mask: one 8B word per lane per query sub-tile, coalesced
    const unsigned long long* mb0 = bitsT + (size_t)kt0 * S + qbase + m0 + l15;
    const unsigned long long* mb1 = mb0 + 16;

    const int ksw_rd = (l15 & 7);               // K/V/P read-write swizzle key
    const float RB = 0.002816949f;              // log2(1+2^-9): pack-round bias
#pragma unroll 1
    for (int kt = kt0; kt < kt1; ++kt) {
        __syncthreads();   // previous tile consumed
        *(uint4*)&Ks[krow0][ksw0] = kq0;
        *(uint4*)&Ks[krow1][ksw1] = kq1;
        {
            const unsigned int* w0 = (const unsigned int*)&vq0;
            const unsigned int* w1 = (const unsigned int*)&vq1;
#pragma unroll
            for (int j = 0; j < 8; ++j) {
                unsigned int pk = __builtin_amdgcn_perm(
                    w1[j >> 1], w0[j >> 1],
                    (j & 1) ? 0x07060302u : 0x05040100u);
                *(unsigned int*)&Vts[vd0 + j][vt0 ^ (j * 8)] = pk;
            }
        }
        if (kt + 1 < kt1) {
            kp0 += 64 * D; kp1 += 64 * D; vp0 += 64 * D; vp1 += 64 * D;
            kq0 = *(const uint4*)kp0;
            kq1 = *(const uint4*)kp1;
            vq0 = *(const uint4*)vp0;
            vq1 = *(const uint4*)vp1;
        }
        unsigned long long mw0 = *mb0; mb0 += S;
        unsigned long long mw1 = *mb1; mb1 += S;
        __syncthreads();   // K/V tile visible

        // S^T = K Q^T (exp2 domain, C-init = RB): A = K frag, B = Q frag.
        // One K-frag read pair feeds BOTH query sub-tiles.
        f32x4 sc[2][4];
        {
            f32x4 z = (f32x4){RB, RB, RB, RB};
            __builtin_amdgcn_s_setprio(1);
#pragma unroll
            for (int nt = 0; nt < 4; ++nt) {
                bf16x8 kb0 = *(bf16x8*)&Ks[nt * 16 + l15][(quad ^ ksw_rd) * 8];
                bf16x8 kb1 = *(bf16x8*)&Ks[nt * 16 + l15][((quad + 4) ^ ksw_rd) * 8];
                sc[0][nt] = __builtin_amdgcn_mfma_f32_16x16x32_bf16(kb0, aq00, z, 0, 0, 0);
                sc[0][nt] = __builtin_amdgcn_mfma_f32_16x16x32_bf16(kb1, aq01, sc[0][nt], 0, 0, 0);
                sc[1][nt] = __builtin_amdgcn_mfma_f32_16x16x32_bf16(kb0, aq10, z, 0, 0, 0);
                sc[1][nt] = __builtin_amdgcn_mfma_f32_16x16x32_bf16(kb1, aq11, sc[1][nt], 0, 0, 0);
            }
            __builtin_amdgcn_s_setprio(0);
        }
        // lane holds P^T: query=l15 (per sub-tile u), tokens nt*16+quad*4+{0..3}.
        // Pack: bits(exp2(sc)) & signext(bit) -> v_perm pair-pack (truncation
        // of x*(1+2^-9) == round-half-up; masked -> 0x0 -> +0 bf16).
#pragma unroll
        for (int u = 0; u < 2; ++u) {
            const unsigned long long sh = (u ? mw1 : mw0) >> (quad * 4);
            const unsigned int wlo = (unsigned int)sh;
            const unsigned int whi = (unsigned int)(sh >> 32);
#pragma unroll
            for (int nt = 0; nt < 4; ++nt) {
                const unsigned int wsel = (nt < 2) ? wlo : whi;
                unsigned int a[4];
#pragma unroll
                for (int r = 0; r < 4; ++r) {
                    const int bit = (nt & 1) * 16 + r;     // compile-time
                    unsigned int m = (unsigned int)((int)(wsel << (31 - bit)) >> 31);
                    a[r] = __float_as_uint(__builtin_amdgcn_exp2f(sc[u][nt][r])) & m;
                }
                uint2 pk;
                pk.x = __builtin_amdgcn_perm(a[1], a[0], 0x07060302u);
                pk.y = __builtin_amdgcn_perm(a[3], a[2], 0x07060302u);
                *(uint2*)&Ps[wid][u * 16 + l15][(nt * 16 + quad * 4) ^ (ksw_rd * 8)] = pk;
            }
        }
        // O += P V ; l += P 1   (P A-frag: row = query, contiguous tokens;
        // read col carries the same XOR key (l15&7)*8)
        bf16x8 ap00 = *(bf16x8*)&Ps[wid][l15][(quad * 8) ^ (ksw_rd * 8)];
        bf16x8 ap01 = *(bf16x8*)&Ps[wid][l15][(32 + quad * 8) ^ (ksw_rd * 8)];
        bf16x8 ap10 = *(bf16x8*)&Ps[wid][16 + l15][(quad * 8) ^ (ksw_rd * 8)];
        bf16x8 ap11 = *(bf16x8*)&Ps[wid][16 + l15][(32 + quad * 8) ^ (ksw_rd * 8)];
        __builtin_amdgcn_s_setprio(1);
        accl[0] = __builtin_amdgcn_mfma_f32_16x16x32_bf16(ap00, bl, accl[0], 0, 0, 0);
        accl[0] = __builtin_amdgcn_mfma_f32_16x16x32_bf16(ap01, bl, accl[0], 0, 0, 0);
        accl[1] = __builtin_amdgcn_mfma_f32_16x16x32_bf16(ap10, bl, accl[1], 0, 0, 0);
        accl[1] = __builtin_amdgcn_mfma_f32_16x16x32_bf16(ap11, bl, accl[1], 0, 0, 0);
#pragma unroll
        for (int dt = 0; dt < 4; ++dt) {
            bf16x8 bv0 = *(bf16x8*)&Vts[dt * 16 + l15][(quad ^ ksw_rd) * 8];
            bf16x8 bv1 = *(bf16x8*)&Vts[dt * 16 + l15][((quad + 4) ^ ksw_rd) * 8];
            o[dt][0] = __builtin_amdgcn_mfma_f32_16x16x32_bf16(ap00, bv0, o[dt][0], 0, 0, 0);
            o[dt][0] = __builtin_amdgcn_mfma_f32_16x16x32_bf16(ap01, bv1, o[dt][0], 0, 0, 0);
            o[dt][1] = __builtin_amdgcn_mfma_f32_16x16x32_bf16(ap10, bv0, o[dt][1], 0, 0, 0);
            o[dt][1] = __builtin_amdgcn_mfma_f32_16x16x32_bf16(ap11, bv1, o[dt][1], 0, 0, 0);
        }
        __builtin_amdgcn_s_setprio(0);
    }
    // epilogue: fp32 partials; O/l C-layout rows = u*16 + quad*4 + r
    float* Op = Opart + (size_t)(split * H + h) * S * D;
    float* Lp = Lpart + (size_t)(split * H + h) * S;
#pragma unroll
    for (int u = 0; u < 2; ++u)
#pragma unroll
        for (int r = 0; r < 4; ++r) {
            int row = qbase + m0 + u * 16 + quad * 4 + r;
            if (l15 == 0) Lp[row] = accl[u][r];
#pragma unroll
            for (int dt = 0; dt < 4; ++dt)
                Op[(size_t)row * D + dt * 16 + l15] = o[dt][u][r];
        }
}

// ---------------------------------------------------------------------------
// combine: one-pass K-split reduction + l-normalization + bf16 cast.
// Ab[row][c] = (sum_s Opart) / (sum_s L), c = h*64 + d.
// grid 1024, block 256: thread -> 8 contiguous cols of one row.
// ---------------------------------------------------------------------------
__global__ __launch_bounds__(256) void combine(const float* __restrict__ Opart,
                                               const float* __restrict__ Lpart,
                                               bf16* __restrict__ Ab, int nsplit)
{
    const size_t oh = (size_t)H * S * D;
    int g = blockIdx.x * 256 + threadIdx.x;       // 262144 threads = S*E/8
    int row = g >> 6;
    int cg  = g & 63;
    int hh  = cg >> 3;
    int d0  = (cg & 7) * 8;
    size_t base = ((size_t)hh * S + row) * D + d0;
    float a[8] = {0.f, 0.f, 0.f, 0.f, 0.f, 0.f, 0.f, 0.f};
    float l = 0.f;
    for (int s = 0; s < nsplit; ++s) {
        float4 p0 = *(const float4*)(Opart + (size_t)s * oh + base);
        float4 p1 = *(const float4*)(Opart + (size_t)s * oh + base + 4);
        a[0] += p0.x; a[1] += p0.y; a[2] += p0.z; a[3] += p0.w;
        a[4] += p1.x; a[5] += p1.y; a[6] += p1.z; a[7] += p1.w;
        l += Lpart[(size_t)s * H * S + (size_t)hh * S + row];
    }
    float inv = (l > 0.f) ? 1.f / l : 0.f;
    union { bf16 hb[8]; uint4 u; } cv;
#pragma unroll
    for (int j = 0; j < 8; ++j) cv.hb[j] = (bf16)(a[j] * inv);
    *(uint4*)&Ab[(size_t)row * E + hh * 64 + d0] = cv.u;
}

// ---------------------------------------------------------------------------
// Output GEMM (r3-best 64x64): out = Ab @ Wo^T + bo, fp32. grid (8, 64).
// ---------------------------------------------------------------------------
__global__ __launch_bounds__(256) void gemm_out(const bf16* __restrict__ A,
                                                const bf16* __restrict__ W,
                                                const bf16* __restrict__ bias,
                                                float* __restrict__ out)
{
    __shared__ bf16 As[64][72];
    __shared__ bf16 Bs[64][72];
    const int tid  = threadIdx.x;
    const int wid  = tid >> 6, lane = tid & 63;
    const int quad = lane >> 4, l15 = lane & 15;
    const int nbase = blockIdx.x * 64;
    const int mbase = blockIdx.y * 64;
    const int m0 = wid * 16;

    f32x4 acc[4];
#pragma unroll
    for (int i = 0; i < 4; ++i) acc[i] = (f32x4){0.f, 0.f, 0.f, 0.f};

    for (int kt = 0; kt < E / 64; ++kt) {
        const int kb = kt * 64;
        __syncthreads();
#pragma unroll
        for (int i = 0; i < 2; ++i) {
            int slot = tid + i * 256;
            int row = slot >> 3, kg = slot & 7;
            *(uint4*)&As[row][kg * 8] = *(const uint4*)&A[(size_t)(mbase + row) * E + kb + kg * 8];
            *(uint4*)&Bs[row][kg * 8] = *(const uint4*)&W[(size_t)(nbase + row) * E + kb + kg * 8];
        }
        __syncthreads();
        bf16x8 a0 = *(bf16x8*)&As[m0 + l15][quad * 8];
        bf16x8 a1 = *(bf16x8*)&As[m0 + l15][32 + quad * 8];
#pragma unroll
        for (int nt = 0; nt < 4; ++nt) {
            bf16x8 b0 = *(bf16x8*)&Bs[nt * 16 + l15][quad * 8];
            bf16x8 b1 = *(bf16x8*)&Bs[nt * 16 + l15][32 + quad * 8];
            acc[nt] = __builtin_amdgcn_mfma_f32_16x16x32_bf16(a0, b0, acc[nt], 0, 0, 0);
            acc[nt] = __builtin_amdgcn_mfma_f32_16x16x32_bf16(a1, b1, acc[nt], 0, 0, 0);
        }
    }
#pragma unroll
    for (int nt = 0; nt < 4; ++nt) {
        int col = nbase + nt * 16 + l15;
        float bv = (float)bias[col];
#pragma unroll
        for (int r = 0; r < 4; ++r) {
            int row = mbase + m0 + quad * 4 + r;
            out[(size_t)row * E + col] = acc[nt][r] + bv;
        }
    }
}

// ---------------------------------------------------------------------------
extern "C" void kernel_launch(void* const* d_in, const int* in_sizes, int n_in,
                              void* d_out, int out_size, void* d_ws, size_t ws_size,
                              hipStream_t stream)
{
    char* ws = (char*)d_ws;
    const size_t MB = (size_t)1 << 20;
    bf16* Qw   = (bf16*)(ws + 0 * MB);        // 12 MB: Q|K|V planar cat
    bf16* Kw   = (bf16*)(ws + 4 * MB);
    bf16* Vw   = (bf16*)(ws + 8 * MB);
    bf16* Ab   = (bf16*)(ws + 12 * MB);       // 4 MB combined attn out (bf16)
    unsigned long long* bitsT = (unsigned long long*)(ws + 16 * MB); // 2 MB
    bf16* xb   = (bf16*)(ws + 18 * MB);       // 4 MB
    bf16* Wcat = (bf16*)(ws + 22 * MB);       // 1.5 MB
    bf16* Wob  = (bf16*)(ws + 24 * MB);       // 0.5 MB
    bf16* bcat = (bf16*)(ws + 25 * MB);
    bf16* bob  = (bf16*)(ws + 25 * MB + 8192);
    float* Opart = (float*)(ws + 26 * MB);    // nsplit x 8 MB

    // 5-way K-split (1280 blocks = exactly 5 blocks/CU with 32 KiB LDS)
    // when the workspace allows; else 4 (r3 behavior); else 2.
    int nsplit = (ws_size >= 68 * MB) ? 5 : (ws_size >= 59 * MB) ? 4 : 2;
    int ktper  = (S / 64 + nsplit - 1) / nsplit;
    float* Lpart = (float*)(ws + 26 * MB + (size_t)nsplit * 8 * MB);

    hipLaunchKernelGGL(prep, dim3(2048), dim3(256), 0, stream,
                       d_in[9], bitsT,
                       (const float*)d_in[0], (const float*)d_in[1],
                       (const float*)d_in[3], (const float*)d_in[5],
                       (const float*)d_in[7], (const float*)d_in[2],
                       (const float*)d_in[4], (const float*)d_in[6],
                       (const float*)d_in[8],
                       xb, Wcat, Wob, bcat, bob);
    hipLaunchKernelGGL(gemm_qkv, dim3(24, 64), dim3(256), 0, stream,
                       xb, Wcat, bcat, Qw);
    hipLaunchKernelGGL(attn, dim3(S / 128, H, nsplit), dim3(256), 0, stream,
                       Qw, Kw, Vw, bitsT, Opart, Lpart, ktper);
    hipLaunchKernelGGL(combine, dim3(1024), dim3(256), 0, stream,
                       Opart, Lpart, Ab, nsplit);
    hipLaunchKernelGGL(gemm_out, dim3(8, 64), dim3(256), 0, stream,
                       Ab, Wob, bob, (float*)d_out);
}

// Round 7
// 256.213 us; speedup vs baseline: 1.7203x; 1.0309x over previous
//
#include <hip/hip_runtime.h>
#include <hip/hip_bf16.h>
#include <stdint.h>

#define S 4096
#define E 512
#define H 8
#define D 64
#define MROW 5000        // mask row stride (MAX_GENES)

typedef __hip_bfloat16 bf16;
typedef __attribute__((ext_vector_type(8))) short bf16x8;
typedef __attribute__((ext_vector_type(4))) float f32x4;

#define CMUL (0.125f * 1.4426950408889634f)  // scale * log2(e), folded into Q

// ---------------------------------------------------------------------------
// prep: all 2048 blocks convert fp32->bf16 (12 MB) via branch-structured
// segment select, then pack mask into TRANSPOSED bit matrix bitsT[word][row].
// ---------------------------------------------------------------------------
__global__ __launch_bounds__(256) void prep(
    const void* __restrict__ mask, unsigned long long* __restrict__ bitsT,
    const float* __restrict__ x,  const float* __restrict__ wq,
    const float* __restrict__ wk, const float* __restrict__ wv,
    const float* __restrict__ wo, const float* __restrict__ bq,
    const float* __restrict__ bk, const float* __restrict__ bv,
    const float* __restrict__ bo,
    bf16* __restrict__ xb, bf16* __restrict__ wcat, bf16* __restrict__ wob,
    bf16* __restrict__ bcat, bf16* __restrict__ bob)
{
    const int tid = threadIdx.x;
    const int b   = blockIdx.x;
    const int gid = b * 256 + tid;
    for (int g = gid; g < 786944; g += 524288) {
        const float* src; bf16* dst; int e;
        if (g < 524288) { src = x; dst = xb; e = g * 4; }
        else {
            int r = g - 524288;
            if      (r < 65536)  { src = wq; dst = wcat;          e = r * 4; }
            else if (r < 131072) { src = wk; dst = wcat + 262144; e = (r - 65536) * 4; }
            else if (r < 196608) { src = wv; dst = wcat + 524288; e = (r - 131072) * 4; }
            else if (r < 262144) { src = wo; dst = wob;           e = (r - 196608) * 4; }
            else if (r < 262272) { src = bq; dst = bcat;          e = (r - 262144) * 4; }
            else if (r < 262400) { src = bk; dst = bcat + 512;    e = (r - 262272) * 4; }
            else if (r < 262528) { src = bv; dst = bcat + 1024;   e = (r - 262400) * 4; }
            else                 { src = bo; dst = bob;           e = (r - 262528) * 4; }
        }
        float4 v = *(const float4*)(src + e);
        union { bf16 h[4]; uint2 u; } cv;
        cv.h[0] = (bf16)v.x; cv.h[1] = (bf16)v.y;
        cv.h[2] = (bf16)v.z; cv.h[3] = (bf16)v.w;
        *(uint2*)(dst + e) = cv.u;
    }
    {
        const unsigned int* mw32 = (const unsigned int*)mask;
        int lane = tid & 63;
        int hit = 0;
#pragma unroll
        for (int i = 0; i < 8; ++i) {
            unsigned int w = mw32[lane + i * 64];
            if (w > 1u && (w & 0xFEFEFEFEu) == 0u) hit = 1;
        }
        const bool isbyte = (__ballot(hit) != 0ull);
        int wid  = (b * 256 + tid) >> 6;
        int nwav = (2048 * 256) >> 6;
        int total = (S / 64) * S;
        for (int w = wid; w < total; w += nwav) {
            int word = w >> 12;          // 0..63
            int row  = w & (S - 1);      // 0..4095
            int col  = word * 64 + lane;
            unsigned int v;
            if (isbyte) v = ((const unsigned char*)mask)[(size_t)row * MROW + col];
            else        v = ((const unsigned int*)mask)[(size_t)row * MROW + col];
            unsigned long long bb = __ballot(v != 0u);
            if (lane == 0) bitsT[(size_t)word * S + row] = bb;
        }
    }
}

// ---------------------------------------------------------------------------
// QKV GEMM: C(64x64 tile) = A(Mx512) @ W^T + bias, N=1536 fused (r3-best).
// out planar Q|K|V, each [h][s][64] bf16; Q pre-scaled by CMUL.
// ---------------------------------------------------------------------------
__global__ __launch_bounds__(256) void gemm_qkv(const bf16* __restrict__ A,
                                                const bf16* __restrict__ W,
                                                const bf16* __restrict__ bias,
                                                bf16* __restrict__ out)
{
    __shared__ bf16 As[64][72];
    __shared__ bf16 Bs[64][72];
    const int tid  = threadIdx.x;
    const int wid  = tid >> 6, lane = tid & 63;
    const int quad = lane >> 4, l15 = lane & 15;
    const int nbase = blockIdx.x * 64;
    const int mbase = blockIdx.y * 64;
    const int m0 = wid * 16;

    f32x4 acc[4];
#pragma unroll
    for (int i = 0; i < 4; ++i) acc[i] = (f32x4){0.f, 0.f, 0.f, 0.f};

    for (int kt = 0; kt < E / 64; ++kt) {
        const int kb = kt * 64;
        __syncthreads();
#pragma unroll
        for (int i = 0; i < 2; ++i) {
            int slot = tid + i * 256;
            int row = slot >> 3, kg = slot & 7;
            *(uint4*)&As[row][kg * 8] = *(const uint4*)&A[(size_t)(mbase + row) * E + kb + kg * 8];
            *(uint4*)&Bs[row][kg * 8] = *(const uint4*)&W[(size_t)(nbase + row) * E + kb + kg * 8];
        }
        __syncthreads();
        bf16x8 a0 = *(bf16x8*)&As[m0 + l15][quad * 8];
        bf16x8 a1 = *(bf16x8*)&As[m0 + l15][32 + quad * 8];
#pragma unroll
        for (int nt = 0; nt < 4; ++nt) {
            bf16x8 b0 = *(bf16x8*)&Bs[nt * 16 + l15][quad * 8];
            bf16x8 b1 = *(bf16x8*)&Bs[nt * 16 + l15][32 + quad * 8];
            acc[nt] = __builtin_amdgcn_mfma_f32_16x16x32_bf16(a0, b0, acc[nt], 0, 0, 0);
            acc[nt] = __builtin_amdgcn_mfma_f32_16x16x32_bf16(a1, b1, acc[nt], 0, 0, 0);
        }
    }
#pragma unroll
    for (int nt = 0; nt < 4; ++nt) {
        int col = nbase + nt * 16 + l15;
        float bv = (float)bias[col];
#pragma unroll
        for (int r = 0; r < 4; ++r) {
            int row = mbase + m0 + quad * 4 + r;
            float v = acc[nt][r] + bv;
            int t = col >> 9, hh = (col >> 6) & 7, d = col & 63;
            if (t == 0) v *= CMUL;
            out[((size_t)t * H + hh) * S * D + (size_t)row * D + d] = (bf16)v;
        }
    }
}

// ---------------------------------------------------------------------------
// Fused flash attention, 32 queries/warp (128/block). Operand-swapped QK
// (P^T layout), pack-round bias folded into QK C-init (RB = log2(1+2^-9)),
// sign-bit mask AND, v_perm pair-pack. NEW: the pack->PV chain is split at
// half-tile granularity — ap00/ap10 (PV tokens 0..31) depend only on the
// nt=0,1 pack writes, ap01/ap11 only on nt=2,3 (verified through the XOR
// swizzle algebra) — so the loop runs QK -> pack01 -> PV slice 0 -> pack23
// -> PV slice 1: slice-1's exp2/pack VALU issues under slice-0's MFMAs,
// breaking the serial QK->pack->PV dependency that left every pipe <40%.
// LDS=32768 (5 blocks/CU with nsplit=5 ragged K-splits).
// grid (S/128, H, nsplit), block 256.
// ---------------------------------------------------------------------------
__global__ __launch_bounds__(256) void attn(const bf16* __restrict__ Qp,
                                            const bf16* __restrict__ Kp,
                                            const bf16* __restrict__ Vp,
                                            const unsigned long long* __restrict__ bitsT,
                                            float* __restrict__ Opart,
                                            float* __restrict__ Lpart,
                                            int ktper)
{
    __shared__ __align__(16) char smem[32768];
    bf16 (*Ps)[32][64] = (bf16(*)[32][64])smem;             // 4 x 32q x 64t swizzled
    bf16 (*Ks)[64]     = (bf16(*)[64])(smem + 16384);       // 64x64 swizzled
    bf16 (*Vts)[64]    = (bf16(*)[64])(smem + 24576);       // 64x64 swizzled V^T

    const int tid  = threadIdx.x;
    const int wid  = tid >> 6, lane = tid & 63;
    const int quad = lane >> 4, l15 = lane & 15;
    const int qb = blockIdx.x, h = blockIdx.y, split = blockIdx.z;
    const int qbase = qb * 128;
    const int m0 = wid * 32;
    const bf16* Qh = Qp + (size_t)h * S * D;
    const bf16* Kh = Kp + (size_t)h * S * D;
    const bf16* Vh = Vp + (size_t)h * S * D;

    const int krow0 = tid >> 3, kkg = tid & 7;
    const int krow1 = (tid + 256) >> 3;
    const int ksw0 = (kkg ^ (krow0 & 7)) * 8;
    const int ksw1 = (kkg ^ (krow1 & 7)) * 8;
    const int vt0 = (tid & 31) * 2, vd0 = (tid >> 5) * 8;

    // Q fragments direct from global: lane = query row (B-operand layout);
    // two query sub-tiles per warp (u=0: rows m0+l15, u=1: rows m0+16+l15)
    const bf16* qr0 = Qh + (size_t)(qbase + m0 + l15) * D;
    bf16x8 aq00 = *(const bf16x8*)(qr0 + quad * 8);
    bf16x8 aq01 = *(const bf16x8*)(qr0 + 32 + quad * 8);
    bf16x8 aq10 = *(const bf16x8*)(qr0 + 16 * D + quad * 8);
    bf16x8 aq11 = *(const bf16x8*)(qr0 + 16 * D + 32 + quad * 8);

    // ones B-fragment for l-sum MFMA (col 0 only)
    bf16x8 bl;
    {
        union { short s; bf16 b; } one; one.b = (bf16)1.0f;
        short v = (l15 == 0) ? one.s : (short)0;
#pragma unroll
        for (int j = 0; j < 8; ++j) bl[j] = v;
    }

    f32x4 o[4][2];
#pragma unroll
    for (int dt = 0; dt < 4; ++dt)
#pragma unroll
        for (int u = 0; u < 2; ++u) o[dt][u] = (f32x4){0.f, 0.f, 0.f, 0.f};
    f32x4 accl[2];
    accl[0] = (f32x4){0.f, 0.f, 0.f, 0.f};
    accl[1] = (f32x4){0.f, 0.f, 0.f, 0.f};

    const int kt0 = split * ktper;
    const int kt1 = min(S / 64, kt0 + ktper);   // ragged tail for nsplit=5

    // strength-reduced prefetch pointers: advance by one K-tile (64*D) per kt
    const bf16* kp0 = Kh + (size_t)(kt0 * 64 + krow0) * D + kkg * 8;
    const bf16* kp1 = Kh + (size_t)(kt0 * 64 + krow1) * D + kkg * 8;
    const bf16* vp0 = Vh + (size_t)(kt0 * 64 + vt0) * D + vd0;
    const bf16* vp1 = Vh + (size_t)(kt0 * 64 + vt0 + 1) * D + vd0;
    uint4 kq0 = *(const uint4*)kp0;
    uint4 kq1 = *(const uint4*)kp1;
    uint4 vq0 = *(const uint4*)vp0;
    uint4 vq1 = *(const uint4*)vp1;

    // transposed mask: one 8B word per lane per query sub-tile, coalesced
    const unsigned long long* mb0 = bitsT + (size_t)kt0 * S + qbase + m0 + l15;
    const unsigned long long* mb1 = mb0 + 16;

    const int ksw_rd = (l15 & 7);               // K/V/P read-write swizzle key
    const float RB = 0.002816949f;              // log2(1+2^-9): pack-round bias
#pragma unroll 1
    for (int kt = kt0; kt < kt1; ++kt) {
        __syncthreads();   // previous tile consumed
        *(uint4*)&Ks[krow0][ksw0] = kq0;
        *(uint4*)&Ks[krow1][ksw1] = kq1;
        {
            const unsigned int* w0 = (const unsigned int*)&vq0;
            const unsigned int* w1 = (const unsigned int*)&vq1;
#pragma unroll
            for (int j = 0; j < 8; ++j) {
                unsigned int pk = __builtin_amdgcn_perm(
                    w1[j >> 1], w0[j >> 1],
                    (j & 1) ? 0x07060302u : 0x05040100u);
                *(unsigned int*)&Vts[vd0 + j][vt0 ^ (j * 8)] = pk;
            }
        }
        if (kt + 1 < kt1) {
            kp0 += 64 * D; kp1 += 64 * D; vp0 += 64 * D; vp1 += 64 * D;
            kq0 = *(const uint4*)kp0;
            kq1 = *(const uint4*)kp1;
            vq0 = *(const uint4*)vp0;
            vq1 = *(const uint4*)vp1;
        }
        unsigned long long mw0 = *mb0; mb0 += S;
        unsigned long long mw1 = *mb1; mb1 += S;
        __syncthreads();   // K/V tile visible

        // S^T = K Q^T (exp2 domain, C-init = RB): A = K frag, B = Q frag.
        f32x4 sc[2][4];
        {
            f32x4 z = (f32x4){RB, RB, RB, RB};
            __builtin_amdgcn_s_setprio(1);
#pragma unroll
            for (int nt = 0; nt < 4; ++nt) {
                bf16x8 kb0 = *(bf16x8*)&Ks[nt * 16 + l15][(quad ^ ksw_rd) * 8];
                bf16x8 kb1 = *(bf16x8*)&Ks[nt * 16 + l15][((quad + 4) ^ ksw_rd) * 8];
                sc[0][nt] = __builtin_amdgcn_mfma_f32_16x16x32_bf16(kb0, aq00, z, 0, 0, 0);
                sc[0][nt] = __builtin_amdgcn_mfma_f32_16x16x32_bf16(kb1, aq01, sc[0][nt], 0, 0, 0);
                sc[1][nt] = __builtin_amdgcn_mfma_f32_16x16x32_bf16(kb0, aq10, z, 0, 0, 0);
                sc[1][nt] = __builtin_amdgcn_mfma_f32_16x16x32_bf16(kb1, aq11, sc[1][nt], 0, 0, 0);
            }
            __builtin_amdgcn_s_setprio(0);
        }
        // Half-tile interleave: pack(nt=0,1) -> PV slice 0 || pack(nt=2,3)
        // -> PV slice 1. Pack: bits(exp2(sc)) & signext(bit) -> v_perm.
#pragma unroll
        for (int half = 0; half < 2; ++half) {
#pragma unroll
            for (int u = 0; u < 2; ++u) {
                const unsigned long long sh = (u ? mw1 : mw0) >> (quad * 4);
                const unsigned int wlo = (unsigned int)sh;
                const unsigned int whi = (unsigned int)(sh >> 32);
#pragma unroll
                for (int ntl = 0; ntl < 2; ++ntl) {
                    const int nt = half * 2 + ntl;
                    const unsigned int wsel = (nt < 2) ? wlo : whi;
                    unsigned int a[4];
#pragma unroll
                    for (int r = 0; r < 4; ++r) {
                        const int bit = (nt & 1) * 16 + r;     // compile-time
                        unsigned int m = (unsigned int)((int)(wsel << (31 - bit)) >> 31);
                        a[r] = __float_as_uint(__builtin_amdgcn_exp2f(sc[u][nt][r])) & m;
                    }
                    uint2 pk;
                    pk.x = __builtin_amdgcn_perm(a[1], a[0], 0x07060302u);
                    pk.y = __builtin_amdgcn_perm(a[3], a[2], 0x07060302u);
                    *(uint2*)&Ps[wid][u * 16 + l15][(nt * 16 + quad * 4) ^ (ksw_rd * 8)] = pk;
                }
            }
            // PV k-slice `half` (tokens half*32..+31): A-frags depend only on
            // the two nt groups just packed (XOR-swizzle-verified mapping).
            const int cu = ((quad + half * 4) ^ ksw_rd) * 8;
            bf16x8 ap0 = *(bf16x8*)&Ps[wid][l15][(quad * 8 + half * 32) ^ (ksw_rd * 8)];
            bf16x8 ap1 = *(bf16x8*)&Ps[wid][16 + l15][(quad * 8 + half * 32) ^ (ksw_rd * 8)];
            __builtin_amdgcn_s_setprio(1);
            accl[0] = __builtin_amdgcn_mfma_f32_16x16x32_bf16(ap0, bl, accl[0], 0, 0, 0);
            accl[1] = __builtin_amdgcn_mfma_f32_16x16x32_bf16(ap1, bl, accl[1], 0, 0, 0);
#pragma unroll
            for (int dt = 0; dt < 4; ++dt) {
                bf16x8 bv = *(bf16x8*)&Vts[dt * 16 + l15][cu];
                o[dt][0] = __builtin_amdgcn_mfma_f32_16x16x32_bf16(ap0, bv, o[dt][0], 0, 0, 0);
                o[dt][1] = __builtin_amdgcn_mfma_f32_16x16x32_bf16(ap1, bv, o[dt][1], 0, 0, 0);
            }
            __builtin_amdgcn_s_setprio(0);
        }
    }
    // epilogue: fp32 partials; O/l C-layout rows = u*16 + quad*4 + r
    float* Op = Opart + (size_t)(split * H + h) * S * D;
    float* Lp = Lpart + (size_t)(split * H + h) * S;
#pragma unroll
    for (int u = 0; u < 2; ++u)
#pragma unroll
        for (int r = 0; r < 4; ++r) {
            int row = qbase + m0 + u * 16 + quad * 4 + r;
            if (l15 == 0) Lp[row] = accl[u][r];
#pragma unroll
            for (int dt = 0; dt < 4; ++dt)
                Op[(size_t)row * D + dt * 16 + l15] = o[dt][u][r];
        }
}

// ---------------------------------------------------------------------------
// combine: one-pass K-split reduction + l-normalization + bf16 cast.
// Ab[row][c] = (sum_s Opart) / (sum_s L), c = h*64 + d.
// grid 1024, block 256: thread -> 8 contiguous cols of one row.
// ---------------------------------------------------------------------------
__global__ __launch_bounds__(256) void combine(const float* __restrict__ Opart,
                                               const float* __restrict__ Lpart,
                                               bf16* __restrict__ Ab, int nsplit)
{
    const size_t oh = (size_t)H * S * D;
    int g = blockIdx.x * 256 + threadIdx.x;       // 262144 threads = S*E/8
    int row = g >> 6;
    int cg  = g & 63;
    int hh  = cg >> 3;
    int d0  = (cg & 7) * 8;
    size_t base = ((size_t)hh * S + row) * D + d0;
    float a[8] = {0.f, 0.f, 0.f, 0.f, 0.f, 0.f, 0.f, 0.f};
    float l = 0.f;
    for (int s = 0; s < nsplit; ++s) {
        float4 p0 = *(const float4*)(Opart + (size_t)s * oh + base);
        float4 p1 = *(const float4*)(Opart + (size_t)s * oh + base + 4);
        a[0] += p0.x; a[1] += p0.y; a[2] += p0.z; a[3] += p0.w;
        a[4] += p1.x; a[5] += p1.y; a[6] += p1.z; a[7] += p1.w;
        l += Lpart[(size_t)s * H * S + (size_t)hh * S + row];
    }
    float inv = (l > 0.f) ? 1.f / l : 0.f;
    union { bf16 hb[8]; uint4 u; } cv;
#pragma unroll
    for (int j = 0; j < 8; ++j) cv.hb[j] = (bf16)(a[j] * inv);
    *(uint4*)&Ab[(size_t)row * E + hh * 64 + d0] = cv.u;
}

// ---------------------------------------------------------------------------
// Output GEMM (r3-best 64x64): out = Ab @ Wo^T + bo, fp32. grid (8, 64).
// ---------------------------------------------------------------------------
__global__ __launch_bounds__(256) void gemm_out(const bf16* __restrict__ A,
                                                const bf16* __restrict__ W,
                                                const bf16* __restrict__ bias,
                                                float* __restrict__ out)
{
    __shared__ bf16 As[64][72];
    __shared__ bf16 Bs[64][72];
    const int tid  = threadIdx.x;
    const int wid  = tid >> 6, lane = tid & 63;
    const int quad = lane >> 4, l15 = lane & 15;
    const int nbase = blockIdx.x * 64;
    const int mbase = blockIdx.y * 64;
    const int m0 = wid * 16;

    f32x4 acc[4];
#pragma unroll
    for (int i = 0; i < 4; ++i) acc[i] = (f32x4){0.f, 0.f, 0.f, 0.f};

    for (int kt = 0; kt < E / 64; ++kt) {
        const int kb = kt * 64;
        __syncthreads();
#pragma unroll
        for (int i = 0; i < 2; ++i) {
            int slot = tid + i * 256;
            int row = slot >> 3, kg = slot & 7;
            *(uint4*)&As[row][kg * 8] = *(const uint4*)&A[(size_t)(mbase + row) * E + kb + kg * 8];
            *(uint4*)&Bs[row][kg * 8] = *(const uint4*)&W[(size_t)(nbase + row) * E + kb + kg * 8];
        }
        __syncthreads();
        bf16x8 a0 = *(bf16x8*)&As[m0 + l15][quad * 8];
        bf16x8 a1 = *(bf16x8*)&As[m0 + l15][32 + quad * 8];
#pragma unroll
        for (int nt = 0; nt < 4; ++nt) {
            bf16x8 b0 = *(bf16x8*)&Bs[nt * 16 + l15][quad * 8];
            bf16x8 b1 = *(bf16x8*)&Bs[nt * 16 + l15][32 + quad * 8];
            acc[nt] = __builtin_amdgcn_mfma_f32_16x16x32_bf16(a0, b0, acc[nt], 0, 0, 0);
            acc[nt] = __builtin_amdgcn_mfma_f32_16x16x32_bf16(a1, b1, acc[nt], 0, 0, 0);
        }
    }
#pragma unroll
    for (int nt = 0; nt < 4; ++nt) {
        int col = nbase + nt * 16 + l15;
        float bv = (float)bias[col];
#pragma unroll
        for (int r = 0; r < 4; ++r) {
            int row = mbase + m0 + quad * 4 + r;
            out[(size_t)row * E + col] = acc[nt][r] + bv;
        }
    }
}

// ---------------------------------------------------------------------------
extern "C" void kernel_launch(void* const* d_in, const int* in_sizes, int n_in,
                              void* d_out, int out_size, void* d_ws, size_t ws_size,
                              hipStream_t stream)
{
    char* ws = (char*)d_ws;
    const size_t MB = (size_t)1 << 20;
    bf16* Qw   = (bf16*)(ws + 0 * MB);        // 12 MB: Q|K|V planar cat
    bf16* Kw   = (bf16*)(ws + 4 * MB);
    bf16* Vw   = (bf16*)(ws + 8 * MB);
    bf16* Ab   = (bf16*)(ws + 12 * MB);       // 4 MB combined attn out (bf16)
    unsigned long long* bitsT = (unsigned long long*)(ws + 16 * MB); // 2 MB
    bf16* xb   = (bf16*)(ws + 18 * MB);       // 4 MB
    bf16* Wcat = (bf16*)(ws + 22 * MB);       // 1.5 MB
    bf16* Wob  = (bf16*)(ws + 24 * MB);       // 0.5 MB
    bf16* bcat = (bf16*)(ws + 25 * MB);
    bf16* bob  = (bf16*)(ws + 25 * MB + 8192);
    float* Opart = (float*)(ws + 26 * MB);    // nsplit x 8 MB

    // 5-way K-split (1280 blocks = exactly 5 blocks/CU with 32 KiB LDS)
    // when the workspace allows; else 4; else 2.
    int nsplit = (ws_size >= 68 * MB) ? 5 : (ws_size >= 59 * MB) ? 4 : 2;
    int ktper  = (S / 64 + nsplit - 1) / nsplit;
    float* Lpart = (float*)(ws + 26 * MB + (size_t)nsplit * 8 * MB);

    hipLaunchKernelGGL(prep, dim3(2048), dim3(256), 0, stream,
                       d_in[9], bitsT,
                       (const float*)d_in[0], (const float*)d_in[1],
                       (const float*)d_in[3], (const float*)d_in[5],
                       (const float*)d_in[7], (const float*)d_in[2],
                       (const float*)d_in[4], (const float*)d_in[6],
                       (const float*)d_in[8],
                       xb, Wcat, Wob, bcat, bob);
    hipLaunchKernelGGL(gemm_qkv, dim3(24, 64), dim3(256), 0, stream,
                       xb, Wcat, bcat, Qw);
    hipLaunchKernelGGL(attn, dim3(S / 128, H, nsplit), dim3(256), 0, stream,
                       Qw, Kw, Vw, bitsT, Opart, Lpart, ktper);
    hipLaunchKernelGGL(combine, dim3(1024), dim3(256), 0, stream,
                       Opart, Lpart, Ab, nsplit);
    hipLaunchKernelGGL(gemm_out, dim3(8, 64), dim3(256), 0, stream,
                       Ab, Wob, bob, (float*)d_out);
}